// Round 4
// baseline (542.565 us; speedup 1.0000x reference)
//
#include <hip/hip_runtime.h>
#include <hip/hip_cooperative_groups.h>
#include <math.h>

namespace cg = cooperative_groups;

// PatchNorm forward (training-mode Welford update + normalize).
// Single cooperative megakernel: bucket-build -> per-cell moments -> normalize,
// with grid.sync() between phases. No fp atomics, no CSR scan, 1 launch.
//
// Shapes (fixed): patches (32,1024,768) fp32, N=32768 tokens, grid 32x32,
// P2=256, C=3. mean/m2 (32,32,256) fp32, out (32,1024,768) fp32.
//
// Closed-form per-cell moments (n_g uniform within a cell):
//   mean_new = mo + (S1 - cnt*mo)/n_g                 S1 = sum_valid xbar
//   m2_new   = m2 + S2 - (mo+mn)*S1 + cnt*mo*mn       S2 = sum_valid xbar^2

#define EPSF 1e-6f

static constexpr int W_GRID = 32;    // grid width (pf = pos_h*W + pos_w)
static constexpr int P2     = 256;   // patch_res^2
static constexpr int P4     = 64;    // P2/4
static constexpr int D4     = 192;   // D/4 float4 chunks per token
static constexpr int HW     = 1024;  // grid cells
static constexpr int NTOK   = 32768; // tokens
static constexpr int MAXTOK = 128;   // bucket capacity (E[cnt]=28.8, max~50)
static constexpr int NBLK   = 1024;  // one block per cell; 4/CU on 256 CUs
static constexpr int NTHR   = 256;

__global__ void __launch_bounds__(NTHR, 4)
k_mega(const float4* __restrict__ patches4,
       const int* __restrict__ pos_h,
       const int* __restrict__ pos_w,
       const int* __restrict__ mask,
       const float* __restrict__ n_old,
       const float* __restrict__ mean_old,
       const float* __restrict__ m2_old,
       float4* __restrict__ out4,
       int* __restrict__ cnt,        // [HW]
       int* __restrict__ pf,         // [NTOK]
       int* __restrict__ list,       // [HW*MAXTOK]
       float* __restrict__ mean_new, // [HW*P2]
       float* __restrict__ inv_std)  // [HW*P2]
{
    cg::grid_group grid = cg::this_grid();
    const int g    = blockIdx.x;     // this block's cell for phase 2
    const int tid  = threadIdx.x;
    const int gtid = g * NTHR + tid;

    __shared__ float4 l14[4][64];
    __shared__ float4 l24[4][64];

    // ---- phase 0: zero own cell counter ------------------------------------
    if (tid == 0) cnt[g] = 0;
    __threadfence();
    grid.sync();

    // ---- phase 1: pf + bucket fill (grid-stride; here: <=1 token/thread) ---
    for (int i = gtid; i < NTOK; i += NBLK * NTHR) {
        const int valid = (mask[i] == 0);
        const int gg = valid ? (pos_h[i] * W_GRID + pos_w[i]) : -1;
        pf[i] = gg;
        if (valid) {
            int slot = atomicAdd(&cnt[gg], 1);
            if (slot < MAXTOK) list[gg * MAXTOK + slot] = i;
        }
    }
    __threadfence();
    grid.sync();

    // ---- phase 2: per-cell moments + fused stats (block g -> cell g) -------
    {
        const int wave = tid >> 6;
        const int lane = tid & 63;
        const int c    = min(cnt[g], MAXTOK);

        float4 s1 = make_float4(0.f, 0.f, 0.f, 0.f);
        float4 s2 = make_float4(0.f, 0.f, 0.f, 0.f);
        for (int k = wave; k < c; k += 4) {
            const int i = list[g * MAXTOK + k];
            const float4* tp = patches4 + (size_t)i * D4;
            float4 a = tp[lane];
            float4 b = tp[lane + P4];
            float4 d = tp[lane + 2 * P4];
            float4 xb;
            xb.x = (a.x + b.x + d.x) * (1.0f / 3.0f);
            xb.y = (a.y + b.y + d.y) * (1.0f / 3.0f);
            xb.z = (a.z + b.z + d.z) * (1.0f / 3.0f);
            xb.w = (a.w + b.w + d.w) * (1.0f / 3.0f);
            s1.x += xb.x; s1.y += xb.y; s1.z += xb.z; s1.w += xb.w;
            s2.x += xb.x * xb.x; s2.y += xb.y * xb.y;
            s2.z += xb.z * xb.z; s2.w += xb.w * xb.w;
        }
        l14[wave][lane] = s1;
        l24[wave][lane] = s2;
        __syncthreads();

        const float* l1f = (const float*)l14;
        const float* l2f = (const float*)l24;
        const float S1 = l1f[tid] + l1f[256 + tid] + l1f[512 + tid] + l1f[768 + tid];
        const float S2 = l2f[tid] + l2f[256 + tid] + l2f[512 + tid] + l2f[768 + tid];

        const float cntf = (float)cnt[g];
        const float nn   = n_old[g] + cntf;
        const float ng   = fmaxf(nn, 1.0f);
        const int   j    = g * P2 + tid;
        const float mo   = mean_old[j];
        const float mn   = mo + (S1 - cntf * mo) / ng;
        const float m2n  = m2_old[j] + (S2 - (mo + mn) * S1 + cntf * mo * mn);
        const float var  = (nn < 2.0f) ? 1.0f : (m2n / ng);
        mean_new[j] = mn;
        inv_std[j]  = 1.0f / (sqrtf(var) + EPSF);
    }
    __threadfence();
    grid.sync();

    // ---- phase 3: normalize (grid-stride over float4 chunk space) ----------
    const float4* mn4 = (const float4*)mean_new;
    const float4* is4 = (const float4*)inv_std;
    for (int c = gtid; c < NTOK * D4; c += NBLK * NTHR) {
        const int token = c / D4;            // const divisor -> magic multiply
        const int t     = c - token * D4;
        const int p4i   = t & 63;
        const int gg    = pf[token];
        const float wv  = (gg >= 0) ? 1.0f : 0.0f;
        const int   gx  = (gg >= 0) ? gg : 0;

        float4 x = patches4[c];
        float4 m = mn4[gx * P4 + p4i];
        float4 s = is4[gx * P4 + p4i];
        float4 o;
        o.x = (x.x - m.x) * s.x * wv;
        o.y = (x.y - m.y) * s.y * wv;
        o.z = (x.z - m.z) * s.z * wv;
        o.w = (x.w - m.w) * s.w * wv;
        out4[c] = o;
    }
}

extern "C" void kernel_launch(void* const* d_in, const int* in_sizes, int n_in,
                              void* d_out, int out_size, void* d_ws, size_t ws_size,
                              hipStream_t stream) {
    const float4* patches4 = (const float4*)d_in[0];
    const int*    pos_h    = (const int*)d_in[1];
    const int*    pos_w    = (const int*)d_in[2];
    const int*    mask     = (const int*)d_in[3];
    const float*  n_old    = (const float*)d_in[4];
    const float*  mean     = (const float*)d_in[5];
    const float*  m2       = (const float*)d_in[6];
    float4* out4 = (float4*)d_out;

    // workspace layout:
    //   int  cnt[HW], pf[NTOK], list[HW*MAXTOK]
    //   f32  mean_new[HW*P2], inv_std[HW*P2]
    int* cnt  = (int*)d_ws;
    int* pf   = cnt + HW;
    int* list = pf + NTOK;
    float* mean_new = (float*)(list + HW * MAXTOK);
    float* inv_std  = mean_new + HW * P2;

    void* args[] = {
        (void*)&patches4, (void*)&pos_h, (void*)&pos_w, (void*)&mask,
        (void*)&n_old, (void*)&mean, (void*)&m2, (void*)&out4,
        (void*)&cnt, (void*)&pf, (void*)&list, (void*)&mean_new, (void*)&inv_std
    };
    hipLaunchCooperativeKernel((const void*)k_mega, dim3(NBLK), dim3(NTHR),
                               args, 0, stream);
}

// Round 5
// 66.701 us; speedup vs baseline: 8.1342x; 8.1342x over previous
//
#include <hip/hip_runtime.h>
#include <math.h>

// PatchNorm forward (training-mode Welford update + normalize).
// 3-kernel pipeline; stream-ordered kernel boundaries serve as the global
// barriers (cg::grid.sync measured ~170us/sync on this stack -- round 4).
//
// Shapes (fixed): patches (32,1024,768) fp32, N=32768 tokens, grid 32x32,
// P2=256, C=3. mean/m2 (32,32,256) fp32, out (32,1024,768) fp32.
//
// Closed-form per-cell moments (n_g uniform within a cell):
//   mean_new = mo + (S1 - cnt*mo)/n_g                 S1 = sum_valid xbar
//   m2_new   = m2 + S2 - (mo+mn)*S1 + cnt*mo*mn       S2 = sum_valid xbar^2

#define EPSF 1e-6f

static constexpr int W_GRID  = 32;    // grid width (pf = pos_h*W + pos_w)
static constexpr int P2      = 256;   // patch_res^2
static constexpr int P4      = 64;    // P2/4
static constexpr int D4      = 192;   // D/4 float4 chunks per token
static constexpr int HW      = 1024;  // grid cells
static constexpr int NTOK    = 32768; // tokens
static constexpr int LISTCAP = 256;   // LDS token-list capacity (E[cnt]=28.8)

// ---- kernel 1: pack per-token cell id (0xFFFF = padded) --------------------
__global__ void k_pf(const int* __restrict__ pos_h,
                     const int* __restrict__ pos_w,
                     const int* __restrict__ mask,
                     unsigned short* __restrict__ pf16) {
    int i = blockIdx.x * blockDim.x + threadIdx.x;
    if (i >= NTOK) return;
    const int valid = (mask[i] == 0);
    pf16[i] = valid ? (unsigned short)(pos_h[i] * W_GRID + pos_w[i])
                    : (unsigned short)0xFFFF;
}

// ---- kernel 2: per-cell scan + gather + fused stats -------------------------
// One block (256 threads = 4 waves) per cell. Each block scans the packed
// pf16 array (int4 = 8 tokens/load; 16 iterations), builds its token list in
// LDS, then gathers those patch rows and reduces moments.
__global__ void __launch_bounds__(256)
k_moments(const float4* __restrict__ patches4,
          const unsigned short* __restrict__ pf16,
          const float* __restrict__ n_old,
          const float* __restrict__ mean_old,
          const float* __restrict__ m2_old,
          float* __restrict__ mean_new,
          float* __restrict__ inv_std) {
    const int g   = blockIdx.x;
    const int tid = threadIdx.x;

    __shared__ int    list[LISTCAP];
    __shared__ int    s_cnt;
    __shared__ float4 l14[4][64];
    __shared__ float4 l24[4][64];

    if (tid == 0) s_cnt = 0;
    __syncthreads();

    // scan: NTOK/8 = 4096 int4-chunks, 256 threads -> 16 iterations
    const int4* pp = (const int4*)pf16;
#pragma unroll
    for (int it = 0; it < 16; ++it) {
        const int idx = it * 256 + tid;       // chunk index
        const int4 v = pp[idx];
        const int base = idx * 8;
#pragma unroll
        for (int k = 0; k < 4; ++k) {
            const int word = (&v.x)[k];
            const int g0 = word & 0xFFFF;
            const int g1 = (word >> 16) & 0xFFFF;
            if (g0 == g) { int s = atomicAdd(&s_cnt, 1); if (s < LISTCAP) list[s] = base + 2 * k; }
            if (g1 == g) { int s = atomicAdd(&s_cnt, 1); if (s < LISTCAP) list[s] = base + 2 * k + 1; }
        }
    }
    __syncthreads();

    const int wave = tid >> 6;
    const int lane = tid & 63;
    const int c = min(s_cnt, LISTCAP);

    float4 s1 = make_float4(0.f, 0.f, 0.f, 0.f);
    float4 s2 = make_float4(0.f, 0.f, 0.f, 0.f);
    for (int k = wave; k < c; k += 4) {
        const int i = list[k];
        const float4* tp = patches4 + (size_t)i * D4;
        float4 a = tp[lane];
        float4 b = tp[lane + P4];
        float4 d = tp[lane + 2 * P4];
        float4 xb;
        xb.x = (a.x + b.x + d.x) * (1.0f / 3.0f);
        xb.y = (a.y + b.y + d.y) * (1.0f / 3.0f);
        xb.z = (a.z + b.z + d.z) * (1.0f / 3.0f);
        xb.w = (a.w + b.w + d.w) * (1.0f / 3.0f);
        s1.x += xb.x; s1.y += xb.y; s1.z += xb.z; s1.w += xb.w;
        s2.x += xb.x * xb.x; s2.y += xb.y * xb.y;
        s2.z += xb.z * xb.z; s2.w += xb.w * xb.w;
    }

    // cross-wave reduce through LDS (float4 stores: conflict-free)
    l14[wave][lane] = s1;
    l24[wave][lane] = s2;
    __syncthreads();

    const float* l1f = (const float*)l14;
    const float* l2f = (const float*)l24;
    const float S1 = l1f[tid] + l1f[256 + tid] + l1f[512 + tid] + l1f[768 + tid];
    const float S2 = l2f[tid] + l2f[256 + tid] + l2f[512 + tid] + l2f[768 + tid];

    const float cnt = (float)c;
    const float nn  = n_old[g] + cnt;
    const float ng  = fmaxf(nn, 1.0f);
    const int   j   = g * P2 + tid;
    const float mo  = mean_old[j];
    const float mn  = mo + (S1 - cnt * mo) / ng;
    const float m2n = m2_old[j] + (S2 - (mo + mn) * S1 + cnt * mo * mn);
    const float var = (nn < 2.0f) ? 1.0f : (m2n / ng);
    mean_new[j] = mn;
    inv_std[j]  = 1.0f / (sqrtf(var) + EPSF);
}

// ---- kernel 3: normalize -----------------------------------------------------
// 192 threads (3 waves) per token; thread t handles float4 chunk t.
__global__ void k_norm(const float4* __restrict__ patches4,
                       const unsigned short* __restrict__ pf16,
                       const float4* __restrict__ mean_new4,
                       const float4* __restrict__ inv_std4,
                       float4* __restrict__ out4) {
    const int i = blockIdx.x;
    const int t = threadIdx.x;                    // 0..191
    const int p4i = t & 63;
    const int gg = pf16[i];
    const float wv = (gg != 0xFFFF) ? 1.0f : 0.0f;
    const int gx = (gg != 0xFFFF) ? gg : 0;

    float4 x = patches4[(size_t)i * D4 + t];
    float4 m = mean_new4[gx * P4 + p4i];
    float4 s = inv_std4[gx * P4 + p4i];
    float4 o;
    o.x = (x.x - m.x) * s.x * wv;
    o.y = (x.y - m.y) * s.y * wv;
    o.z = (x.z - m.z) * s.z * wv;
    o.w = (x.w - m.w) * s.w * wv;
    out4[(size_t)i * D4 + t] = o;
}

extern "C" void kernel_launch(void* const* d_in, const int* in_sizes, int n_in,
                              void* d_out, int out_size, void* d_ws, size_t ws_size,
                              hipStream_t stream) {
    const float4* patches4 = (const float4*)d_in[0];
    const int*    pos_h    = (const int*)d_in[1];
    const int*    pos_w    = (const int*)d_in[2];
    const int*    mask     = (const int*)d_in[3];
    const float*  n_old    = (const float*)d_in[4];
    const float*  mean     = (const float*)d_in[5];
    const float*  m2       = (const float*)d_in[6];
    float4* out4 = (float4*)d_out;

    // workspace layout:
    //   ushort pf16[NTOK]  (64 KB)
    //   f32    mean_new[HW*P2], inv_std[HW*P2]
    unsigned short* pf16 = (unsigned short*)d_ws;
    float* mean_new = (float*)(pf16 + NTOK);
    float* inv_std  = mean_new + (size_t)HW * P2;

    k_pf<<<(NTOK + 255) / 256, 256, 0, stream>>>(pos_h, pos_w, mask, pf16);
    k_moments<<<HW, 256, 0, stream>>>(patches4, pf16, n_old, mean, m2,
                                      mean_new, inv_std);
    k_norm<<<NTOK, 192, 0, stream>>>(patches4, pf16,
                                     (const float4*)mean_new,
                                     (const float4*)inv_std, out4);
}

// Round 6
// 61.960 us; speedup vs baseline: 8.7566x; 1.0765x over previous
//
#include <hip/hip_runtime.h>
#include <math.h>

// PatchNorm forward (training-mode Welford update + normalize), 2 kernels:
//   k_pf:   pack per-token cell id into ushort (0xFFFF = padded)
//   k_cell: one block per grid cell -- scan pf16 -> token list in LDS ->
//           gather rows (S1/S2 moments) -> closed-form stats in LDS ->
//           normalize the SAME rows (L2-hot re-read) -> write out.
//           Also zeroes padded tokens in its 32-token slice.
// Updated stats (mean_new/m2_new) are never an output -> kept in LDS only.
//
// Shapes (fixed): patches (32,1024,768) fp32, N=32768 tokens, grid 32x32,
// P2=256, C=3. mean/m2 (32,32,256) fp32, out (32,1024,768) fp32.
//
// Closed-form per-cell moments (n_g uniform within a cell):
//   mean_new = mo + (S1 - cnt*mo)/n_g                 S1 = sum_valid xbar
//   m2_new   = m2 + S2 - (mo+mn)*S1 + cnt*mo*mn       S2 = sum_valid xbar^2

#define EPSF 1e-6f

static constexpr int W_GRID  = 32;    // grid width (pf = pos_h*W + pos_w)
static constexpr int P2      = 256;   // patch_res^2
static constexpr int P4      = 64;    // P2/4
static constexpr int D4      = 192;   // D/4 float4 chunks per token
static constexpr int HW      = 1024;  // grid cells
static constexpr int NTOK    = 32768; // tokens
static constexpr int LISTCAP = 96;    // token-list capacity (E[cnt]=28.8, max~50)
static constexpr int SLICE   = NTOK / HW; // 32 tokens/block for pad-zeroing

// ---- kernel 1: pack per-token cell id (0xFFFF = padded) --------------------
__global__ void k_pf(const int* __restrict__ pos_h,
                     const int* __restrict__ pos_w,
                     const int* __restrict__ mask,
                     unsigned short* __restrict__ pf16) {
    int i = blockIdx.x * blockDim.x + threadIdx.x;
    if (i >= NTOK) return;
    const int valid = (mask[i] == 0);
    pf16[i] = valid ? (unsigned short)(pos_h[i] * W_GRID + pos_w[i])
                    : (unsigned short)0xFFFF;
}

// ---- kernel 2: fused per-cell moments + stats + normalize ------------------
__global__ void __launch_bounds__(256, 4)
k_cell(const float4* __restrict__ patches4,
       const unsigned short* __restrict__ pf16,
       const float* __restrict__ n_old,
       const float* __restrict__ mean_old,
       const float* __restrict__ m2_old,
       float4* __restrict__ out4) {
    const int g    = blockIdx.x;
    const int tid  = threadIdx.x;
    const int wave = tid >> 6;
    const int lane = tid & 63;

    __shared__ int            list[LISTCAP];
    __shared__ int            s_cnt;
    __shared__ unsigned short s_slice[SLICE];
    __shared__ float4         l14[4][64];
    __shared__ float4         l24[4][64];
    __shared__ float4         mn_s[P4];
    __shared__ float4         is_s[P4];

    if (tid == 0) s_cnt = 0;
    if (tid < SLICE) s_slice[tid] = pf16[g * SLICE + tid];
    __syncthreads();

    // ---- pad-zeroing for this block's 32-token slice -----------------------
#pragma unroll
    for (int t = 0; t < SLICE; ++t) {
        if (s_slice[t] == 0xFFFF) {
            const int i = g * SLICE + t;
            if (tid < D4)
                out4[(size_t)i * D4 + tid] = make_float4(0.f, 0.f, 0.f, 0.f);
        }
    }

    // ---- scan pf16 (int4 = 8 tokens/load; 4096 chunks / 256 thr = 16 it) ---
    const int4* pp = (const int4*)pf16;
#pragma unroll
    for (int it = 0; it < 16; ++it) {
        const int idx = it * 256 + tid;
        const int4 v = pp[idx];
        const int base = idx * 8;
#pragma unroll
        for (int k = 0; k < 4; ++k) {
            const int word = (&v.x)[k];
            const int g0 = word & 0xFFFF;
            const int g1 = (word >> 16) & 0xFFFF;
            if (g0 == g) { int s = atomicAdd(&s_cnt, 1); if (s < LISTCAP) list[s] = base + 2 * k; }
            if (g1 == g) { int s = atomicAdd(&s_cnt, 1); if (s < LISTCAP) list[s] = base + 2 * k + 1; }
        }
    }
    __syncthreads();
    const int c = min(s_cnt, LISTCAP);

    // ---- gather: accumulate S1/S2 over this cell's tokens ------------------
    float4 s1 = make_float4(0.f, 0.f, 0.f, 0.f);
    float4 s2 = make_float4(0.f, 0.f, 0.f, 0.f);
    for (int k = wave; k < c; k += 4) {
        const int i = list[k];
        const float4* tp = patches4 + (size_t)i * D4;
        float4 a = tp[lane];
        float4 b = tp[lane + P4];
        float4 d = tp[lane + 2 * P4];
        float4 xb;
        xb.x = (a.x + b.x + d.x) * (1.0f / 3.0f);
        xb.y = (a.y + b.y + d.y) * (1.0f / 3.0f);
        xb.z = (a.z + b.z + d.z) * (1.0f / 3.0f);
        xb.w = (a.w + b.w + d.w) * (1.0f / 3.0f);
        s1.x += xb.x; s1.y += xb.y; s1.z += xb.z; s1.w += xb.w;
        s2.x += xb.x * xb.x; s2.y += xb.y * xb.y;
        s2.z += xb.z * xb.z; s2.w += xb.w * xb.w;
    }

    // ---- cross-wave reduce + closed-form stats (tid = p index) -------------
    l14[wave][lane] = s1;
    l24[wave][lane] = s2;
    __syncthreads();

    {
        const float* l1f = (const float*)l14;
        const float* l2f = (const float*)l24;
        const float S1 = l1f[tid] + l1f[256 + tid] + l1f[512 + tid] + l1f[768 + tid];
        const float S2 = l2f[tid] + l2f[256 + tid] + l2f[512 + tid] + l2f[768 + tid];

        const float cnt = (float)c;
        const float nn  = n_old[g] + cnt;
        const float ng  = fmaxf(nn, 1.0f);
        const int   j   = g * P2 + tid;
        const float mo  = mean_old[j];
        const float mn  = mo + (S1 - cnt * mo) / ng;
        const float m2n = m2_old[j] + (S2 - (mo + mn) * S1 + cnt * mo * mn);
        const float var = (nn < 2.0f) ? 1.0f : (m2n / ng);
        ((float*)mn_s)[tid] = mn;
        ((float*)is_s)[tid] = 1.0f / (sqrtf(var) + EPSF);
    }
    __syncthreads();

    // ---- normalize the same rows (L2-hot re-read) --------------------------
    const float4 m4 = mn_s[lane];
    const float4 s4 = is_s[lane];
    for (int k = wave; k < c; k += 4) {
        const int i = list[k];
        const float4* tp = patches4 + (size_t)i * D4;
        float4* op = out4 + (size_t)i * D4;
#pragma unroll
        for (int ch = 0; ch < 3; ++ch) {
            float4 x = tp[lane + ch * P4];
            float4 o;
            o.x = (x.x - m4.x) * s4.x;
            o.y = (x.y - m4.y) * s4.y;
            o.z = (x.z - m4.z) * s4.z;
            o.w = (x.w - m4.w) * s4.w;
            op[lane + ch * P4] = o;
        }
    }
}

extern "C" void kernel_launch(void* const* d_in, const int* in_sizes, int n_in,
                              void* d_out, int out_size, void* d_ws, size_t ws_size,
                              hipStream_t stream) {
    const float4* patches4 = (const float4*)d_in[0];
    const int*    pos_h    = (const int*)d_in[1];
    const int*    pos_w    = (const int*)d_in[2];
    const int*    mask     = (const int*)d_in[3];
    const float*  n_old    = (const float*)d_in[4];
    const float*  mean     = (const float*)d_in[5];
    const float*  m2       = (const float*)d_in[6];
    float4* out4 = (float4*)d_out;

    // workspace: ushort pf16[NTOK] (64 KB)
    unsigned short* pf16 = (unsigned short*)d_ws;

    k_pf<<<NTOK / 256, 256, 0, stream>>>(pos_h, pos_w, mask, pf16);
    k_cell<<<HW, 256, 0, stream>>>(patches4, pf16, n_old, mean, m2, out4);
}

// Round 7
// 58.852 us; speedup vs baseline: 9.2191x; 1.0528x over previous
//
#include <hip/hip_runtime.h>
#include <math.h>

// PatchNorm forward (training-mode Welford update + normalize), 2 kernels:
//   k_pf:   pack per-token cell id into ushort (0xFFFF = padded)
//   k_cell: one block per grid cell -- scan pf16 -> token list in LDS ->
//           gather rows (S1/S2 moments, 4-deep batched loads) -> closed-form
//           stats in LDS -> normalize the SAME rows (L2-hot, 2-deep batched).
// Round-6 lesson: VGPR=16 => compiler issued loads serially (latency-bound,
// 30% HBM). This version manually batches loads to force deep MLP.
//
// Closed-form per-cell moments (n_g uniform within a cell):
//   mean_new = mo + (S1 - cnt*mo)/n_g                 S1 = sum_valid xbar
//   m2_new   = m2 + S2 - (mo+mn)*S1 + cnt*mo*mn       S2 = sum_valid xbar^2

#define EPSF 1e-6f

static constexpr int W_GRID  = 32;    // grid width (pf = pos_h*W + pos_w)
static constexpr int P2      = 256;   // patch_res^2
static constexpr int P4      = 64;    // P2/4
static constexpr int D4      = 192;   // D/4 float4 chunks per token
static constexpr int HW      = 1024;  // grid cells
static constexpr int NTOK    = 32768; // tokens
static constexpr int LISTCAP = 96;    // token-list capacity (E[cnt]=28.8, max~50)
static constexpr int SLICE   = NTOK / HW; // 32 tokens/block for pad-zeroing

// ---- kernel 1: pack per-token cell id (0xFFFF = padded) --------------------
__global__ void k_pf(const int* __restrict__ pos_h,
                     const int* __restrict__ pos_w,
                     const int* __restrict__ mask,
                     unsigned short* __restrict__ pf16) {
    int i = blockIdx.x * blockDim.x + threadIdx.x;
    if (i >= NTOK) return;
    const int valid = (mask[i] == 0);
    pf16[i] = valid ? (unsigned short)(pos_h[i] * W_GRID + pos_w[i])
                    : (unsigned short)0xFFFF;
}

// ---- kernel 2: fused per-cell moments + stats + normalize ------------------
__global__ void __launch_bounds__(256, 4)
k_cell(const float4* __restrict__ patches4,
       const unsigned short* __restrict__ pf16,
       const float* __restrict__ n_old,
       const float* __restrict__ mean_old,
       const float* __restrict__ m2_old,
       float4* __restrict__ out4) {
    const int g    = blockIdx.x;
    const int tid  = threadIdx.x;
    const int wave = tid >> 6;
    const int lane = tid & 63;

    __shared__ int            list[LISTCAP];
    __shared__ int            s_cnt;
    __shared__ unsigned short s_slice[SLICE];
    __shared__ float4         l14[4][64];
    __shared__ float4         l24[4][64];
    __shared__ float4         mn_s[P4];
    __shared__ float4         is_s[P4];

    if (tid == 0) s_cnt = 0;
    if (tid < SLICE) s_slice[tid] = pf16[g * SLICE + tid];

    // ---- issue ALL scan loads up front (16 independent L2 loads in flight) -
    const int4* pp = (const int4*)pf16;
    int4 v[16];
#pragma unroll
    for (int it = 0; it < 16; ++it) v[it] = pp[it * 256 + tid];

    __syncthreads();

    // ---- pad-zeroing for this block's 32-token slice (overlaps scan loads) -
#pragma unroll
    for (int t = 0; t < SLICE; ++t) {
        if (s_slice[t] == 0xFFFF) {
            const int i = g * SLICE + t;
            if (tid < D4)
                out4[(size_t)i * D4 + tid] = make_float4(0.f, 0.f, 0.f, 0.f);
        }
    }

    // ---- process scan chunks -> LDS token list -----------------------------
#pragma unroll
    for (int it = 0; it < 16; ++it) {
        const int base = (it * 256 + tid) * 8;
#pragma unroll
        for (int k = 0; k < 4; ++k) {
            const int word = (&v[it].x)[k];
            const int g0 = word & 0xFFFF;
            const int g1 = (word >> 16) & 0xFFFF;
            if (g0 == g) { int s = atomicAdd(&s_cnt, 1); if (s < LISTCAP) list[s] = base + 2 * k; }
            if (g1 == g) { int s = atomicAdd(&s_cnt, 1); if (s < LISTCAP) list[s] = base + 2 * k + 1; }
        }
    }
    __syncthreads();
    const int c = min(s_cnt, LISTCAP);

    // ---- gather: S1/S2 moments, 4 tokens in flight per wave ----------------
    float4 s1 = make_float4(0.f, 0.f, 0.f, 0.f);
    float4 s2 = make_float4(0.f, 0.f, 0.f, 0.f);
    int k = wave;
    for (; k + 12 < c; k += 16) {
        int idx4[4];
        idx4[0] = list[k];     idx4[1] = list[k + 4];
        idx4[2] = list[k + 8]; idx4[3] = list[k + 12];
        float4 A[4], B[4], Dd[4];
#pragma unroll
        for (int j = 0; j < 4; ++j) {
            const float4* tp = patches4 + (size_t)idx4[j] * D4;
            A[j]  = tp[lane];
            B[j]  = tp[lane + P4];
            Dd[j] = tp[lane + 2 * P4];
        }
#pragma unroll
        for (int j = 0; j < 4; ++j) {
            float4 xb;
            xb.x = (A[j].x + B[j].x + Dd[j].x) * (1.0f / 3.0f);
            xb.y = (A[j].y + B[j].y + Dd[j].y) * (1.0f / 3.0f);
            xb.z = (A[j].z + B[j].z + Dd[j].z) * (1.0f / 3.0f);
            xb.w = (A[j].w + B[j].w + Dd[j].w) * (1.0f / 3.0f);
            s1.x += xb.x; s1.y += xb.y; s1.z += xb.z; s1.w += xb.w;
            s2.x += xb.x * xb.x; s2.y += xb.y * xb.y;
            s2.z += xb.z * xb.z; s2.w += xb.w * xb.w;
        }
    }
    for (; k < c; k += 4) {
        const int i = list[k];
        const float4* tp = patches4 + (size_t)i * D4;
        float4 a = tp[lane];
        float4 b = tp[lane + P4];
        float4 d = tp[lane + 2 * P4];
        float4 xb;
        xb.x = (a.x + b.x + d.x) * (1.0f / 3.0f);
        xb.y = (a.y + b.y + d.y) * (1.0f / 3.0f);
        xb.z = (a.z + b.z + d.z) * (1.0f / 3.0f);
        xb.w = (a.w + b.w + d.w) * (1.0f / 3.0f);
        s1.x += xb.x; s1.y += xb.y; s1.z += xb.z; s1.w += xb.w;
        s2.x += xb.x * xb.x; s2.y += xb.y * xb.y;
        s2.z += xb.z * xb.z; s2.w += xb.w * xb.w;
    }

    // ---- cross-wave reduce + closed-form stats (tid = p index) -------------
    l14[wave][lane] = s1;
    l24[wave][lane] = s2;
    __syncthreads();

    {
        const float* l1f = (const float*)l14;
        const float* l2f = (const float*)l24;
        const float S1 = l1f[tid] + l1f[256 + tid] + l1f[512 + tid] + l1f[768 + tid];
        const float S2 = l2f[tid] + l2f[256 + tid] + l2f[512 + tid] + l2f[768 + tid];

        const float cnt = (float)c;
        const float nn  = n_old[g] + cnt;
        const float ng  = fmaxf(nn, 1.0f);
        const int   j   = g * P2 + tid;
        const float mo  = mean_old[j];
        const float mn  = mo + (S1 - cnt * mo) / ng;
        const float m2n = m2_old[j] + (S2 - (mo + mn) * S1 + cnt * mo * mn);
        const float var = (nn < 2.0f) ? 1.0f : (m2n / ng);
        ((float*)mn_s)[tid] = mn;
        ((float*)is_s)[tid] = 1.0f / (sqrtf(var) + EPSF);
    }
    __syncthreads();

    // ---- normalize the same rows (L2-hot), 2 tokens in flight per wave -----
    const float4 m4 = mn_s[lane];
    const float4 s4 = is_s[lane];
    k = wave;
    for (; k + 4 < c; k += 8) {
        const int i0 = list[k], i1 = list[k + 4];
        const float4* t0 = patches4 + (size_t)i0 * D4;
        const float4* t1 = patches4 + (size_t)i1 * D4;
        float4 x0 = t0[lane], x1 = t0[lane + P4], x2 = t0[lane + 2 * P4];
        float4 y0 = t1[lane], y1 = t1[lane + P4], y2 = t1[lane + 2 * P4];
        float4* o0 = out4 + (size_t)i0 * D4;
        float4* o1 = out4 + (size_t)i1 * D4;
        float4 r;
        r.x = (x0.x - m4.x) * s4.x; r.y = (x0.y - m4.y) * s4.y;
        r.z = (x0.z - m4.z) * s4.z; r.w = (x0.w - m4.w) * s4.w;
        o0[lane] = r;
        r.x = (x1.x - m4.x) * s4.x; r.y = (x1.y - m4.y) * s4.y;
        r.z = (x1.z - m4.z) * s4.z; r.w = (x1.w - m4.w) * s4.w;
        o0[lane + P4] = r;
        r.x = (x2.x - m4.x) * s4.x; r.y = (x2.y - m4.y) * s4.y;
        r.z = (x2.z - m4.z) * s4.z; r.w = (x2.w - m4.w) * s4.w;
        o0[lane + 2 * P4] = r;
        r.x = (y0.x - m4.x) * s4.x; r.y = (y0.y - m4.y) * s4.y;
        r.z = (y0.z - m4.z) * s4.z; r.w = (y0.w - m4.w) * s4.w;
        o1[lane] = r;
        r.x = (y1.x - m4.x) * s4.x; r.y = (y1.y - m4.y) * s4.y;
        r.z = (y1.z - m4.z) * s4.z; r.w = (y1.w - m4.w) * s4.w;
        o1[lane + P4] = r;
        r.x = (y2.x - m4.x) * s4.x; r.y = (y2.y - m4.y) * s4.y;
        r.z = (y2.z - m4.z) * s4.z; r.w = (y2.w - m4.w) * s4.w;
        o1[lane + 2 * P4] = r;
    }
    for (; k < c; k += 4) {
        const int i = list[k];
        const float4* tp = patches4 + (size_t)i * D4;
        float4* op = out4 + (size_t)i * D4;
#pragma unroll
        for (int ch = 0; ch < 3; ++ch) {
            float4 x = tp[lane + ch * P4];
            float4 r;
            r.x = (x.x - m4.x) * s4.x; r.y = (x.y - m4.y) * s4.y;
            r.z = (x.z - m4.z) * s4.z; r.w = (x.w - m4.w) * s4.w;
            op[lane + ch * P4] = r;
        }
    }
}

extern "C" void kernel_launch(void* const* d_in, const int* in_sizes, int n_in,
                              void* d_out, int out_size, void* d_ws, size_t ws_size,
                              hipStream_t stream) {
    const float4* patches4 = (const float4*)d_in[0];
    const int*    pos_h    = (const int*)d_in[1];
    const int*    pos_w    = (const int*)d_in[2];
    const int*    mask     = (const int*)d_in[3];
    const float*  n_old    = (const float*)d_in[4];
    const float*  mean     = (const float*)d_in[5];
    const float*  m2       = (const float*)d_in[6];
    float4* out4 = (float4*)d_out;

    // workspace: ushort pf16[NTOK] (64 KB)
    unsigned short* pf16 = (unsigned short*)d_ws;

    k_pf<<<NTOK / 256, 256, 0, stream>>>(pos_h, pos_w, mask, pf16);
    k_cell<<<HW, 256, 0, stream>>>(patches4, pf16, n_old, mean, m2, out4);
}